// Round 1
// baseline (1802.800 us; speedup 1.0000x reference)
//
#include <hip/hip_runtime.h>
#include <hip/hip_bf16.h>

#define D 256
#define D4 64
#define EPB 16
#define RPB 32
#define BN_EPS 1e-5f

__device__ __forceinline__ void atomAddF(float* p, float v) {
    unsafeAtomicAdd(p, v);  // global_atomic_add_f32 on gfx950
}

// ---------------------------------------------------------------------------
// K1: W_le[j][d] = sum_k loop_rel[(j+k)%256] * w_loop[k][d]
// ---------------------------------------------------------------------------
__global__ __launch_bounds__(256) void wle_kernel(
    const float* __restrict__ loop_rel, const float* __restrict__ w_loop,
    float* __restrict__ W_le) {
    __shared__ float lr[D];
    const int d = threadIdx.x, j = blockIdx.x;
    lr[d] = loop_rel[d];
    __syncthreads();
    float acc = 0.f;
#pragma unroll 4
    for (int k = 0; k < D; ++k)
        acc = fmaf(lr[(j + k) & 255], w_loop[k * D + d], acc);
    W_le[j * D + d] = acc;
}

// ---------------------------------------------------------------------------
// corr8: acc[c] += x[jj] * w[jj+c], jj in [0,8), c in [0,8); w = 16-float window
// all indices compile-time after unroll -> registers only
// ---------------------------------------------------------------------------
__device__ __forceinline__ void corr8(const float4 xa, const float4 xb,
                                      const float4 w0, const float4 w1,
                                      const float4 w2, const float4 w3,
                                      float acc[8]) {
    const float x[8] = {xa.x, xa.y, xa.z, xa.w, xb.x, xb.y, xb.z, xb.w};
    const float w[16] = {w0.x, w0.y, w0.z, w0.w, w1.x, w1.y, w1.z, w1.w,
                         w2.x, w2.y, w2.z, w2.w, w3.x, w3.y, w3.z, w3.w};
#pragma unroll
    for (int jj = 0; jj < 8; ++jj)
#pragma unroll
        for (int c = 0; c < 8; ++c)
            acc[c] = fmaf(x[jj], w[jj + c], acc[c]);
}

// ---------------------------------------------------------------------------
// K2: per-edge msg = ccorr(node_ft[src], edge_ft) @ w_in, atomic scatter to agg
// 16 edges per block of 256 threads.
// ---------------------------------------------------------------------------
__global__ __launch_bounds__(256) void edge_kernel(
    const float* __restrict__ node_ft, const float* __restrict__ edge_ft,
    const float* __restrict__ w_in, const int* __restrict__ src,
    const int* __restrict__ dst, float* __restrict__ agg, int E) {
    __shared__ float4 xs[EPB * 64];   // src features; reused as w_in tile later
    __shared__ float4 ys[EPB * 65];   // edge features (row pad: 65 f4 -> bank spread)
    __shared__ float4 cs[EPB * 65];   // ccorr results (padded)
    __shared__ int sd[2][EPB];

    const int tid = threadIdx.x;
    const int ebase = blockIdx.x * EPB;

    if (tid < EPB) {
        int e = ebase + tid;
        int ee = (e < E) ? e : 0;
        sd[0][tid] = src[ee];
        sd[1][tid] = dst[ee];
    }
    __syncthreads();

    // ---- load features (coalesced float4) ----
    {
        const float4* nf4 = (const float4*)node_ft;
        const float4* ef4 = (const float4*)edge_ft;
        const int c4 = tid & 63, e0 = tid >> 6;
#pragma unroll
        for (int p = 0; p < 4; ++p) {
            int e = e0 + 4 * p;
            int srow = sd[0][e];
            xs[e * 64 + c4] = nf4[(long long)srow * 64 + c4];
            int ge = ebase + e;
            if (ge >= E) ge = 0;
            ys[e * 65 + c4] = ef4[(long long)ge * 64 + c4];
        }
    }
    __syncthreads();

    // ---- ccorr: thread covers k = 8l..8l+7 of edge es; 32 threads/edge ----
    const int l = tid & 31;
    const int es0 = tid >> 5;
#pragma unroll
    for (int pass = 0; pass < 2; ++pass) {
        const int es = es0 + 8 * pass;
        const float4* yrow = &ys[es * 65];
        const float4* xrow = &xs[es * 64];
        float acc[8] = {0.f, 0.f, 0.f, 0.f, 0.f, 0.f, 0.f, 0.f};
        int fb = 2 * l;  // window start in float4 units (= (j0 + 8l)/4)
        float4 A = yrow[fb & 63], B = yrow[(fb + 1) & 63];
        float4 C = yrow[(fb + 2) & 63], Dv = yrow[(fb + 3) & 63];
        for (int j0 = 0; j0 < 256; j0 += 16) {
            float4 xa = xrow[(j0 >> 2) + 0], xb = xrow[(j0 >> 2) + 1];
            corr8(xa, xb, A, B, C, Dv, acc);
            A = yrow[(fb + 4) & 63];
            B = yrow[(fb + 5) & 63];
            float4 xc = xrow[(j0 >> 2) + 2], xd = xrow[(j0 >> 2) + 3];
            corr8(xc, xd, C, Dv, A, B, acc);
            C = yrow[(fb + 6) & 63];
            Dv = yrow[(fb + 7) & 63];
            fb += 4;
        }
        cs[es * 65 + 2 * l + 0] = make_float4(acc[0], acc[1], acc[2], acc[3]);
        cs[es * 65 + 2 * l + 1] = make_float4(acc[4], acc[5], acc[6], acc[7]);
    }

    // ---- matmul: msg[e][d] = sum_k cs[e][k] * w_in[k][d] ----
    float4* wt = xs;  // alias (xs no longer needed after barrier below)
    const int dg = tid & 63;  // d = 4*dg .. 4*dg+3
    const int eg = tid >> 6;  // edges 4*eg .. 4*eg+3
    float macc[16];
#pragma unroll
    for (int i = 0; i < 16; ++i) macc[i] = 0.f;
    const float4* wi4 = (const float4*)w_in;

    for (int k0 = 0; k0 < 256; k0 += 16) {
        __syncthreads();  // prev-chunk compute (and ccorr xs reads) done
#pragma unroll
        for (int q = 0; q < 4; ++q) {
            int idx = tid + 256 * q;
            int kk = idx >> 6, c4 = idx & 63;
            wt[kk * 64 + c4] = wi4[(k0 + kk) * 64 + c4];
        }
        __syncthreads();
#pragma unroll
        for (int kk = 0; kk < 16; kk += 4) {
            float4 w0 = wt[(kk + 0) * 64 + dg];
            float4 w1 = wt[(kk + 1) * 64 + dg];
            float4 w2 = wt[(kk + 2) * 64 + dg];
            float4 w3 = wt[(kk + 3) * 64 + dg];
#pragma unroll
            for (int i = 0; i < 4; ++i) {
                int e = eg * 4 + i;
                float4 cv = cs[e * 65 + ((k0 + kk) >> 2)];  // wave-uniform bcast
                macc[i * 4 + 0] = fmaf(cv.x, w0.x, fmaf(cv.y, w1.x, fmaf(cv.z, w2.x, fmaf(cv.w, w3.x, macc[i * 4 + 0]))));
                macc[i * 4 + 1] = fmaf(cv.x, w0.y, fmaf(cv.y, w1.y, fmaf(cv.z, w2.y, fmaf(cv.w, w3.y, macc[i * 4 + 1]))));
                macc[i * 4 + 2] = fmaf(cv.x, w0.z, fmaf(cv.y, w1.z, fmaf(cv.z, w2.z, fmaf(cv.w, w3.z, macc[i * 4 + 2]))));
                macc[i * 4 + 3] = fmaf(cv.x, w0.w, fmaf(cv.y, w1.w, fmaf(cv.z, w2.w, fmaf(cv.w, w3.w, macc[i * 4 + 3]))));
            }
        }
    }

    // ---- scatter: agg[dst[e]][4dg..4dg+3] += msg ----
#pragma unroll
    for (int i = 0; i < 4; ++i) {
        int e = eg * 4 + i;
        if (ebase + e < E) {
            int drow = sd[1][e];
            float* p = agg + (long long)drow * D + dg * 4;
            atomAddF(p + 0, macc[i * 4 + 0]);
            atomAddF(p + 1, macc[i * 4 + 1]);
            atomAddF(p + 2, macc[i * 4 + 2]);
            atomAddF(p + 3, macc[i * 4 + 3]);
        }
    }
}

// ---------------------------------------------------------------------------
// K3: h = agg*norm + bias + node_ft@W_le  (in-place over agg in d_out),
//     plus per-column sum / sumsq partials for BN.
// ---------------------------------------------------------------------------
__global__ __launch_bounds__(256) void node_kernel(
    const float* __restrict__ node_ft, const float* __restrict__ W_le,
    const float* __restrict__ norm, const float* __restrict__ w_bias,
    float* __restrict__ hbuf, float* __restrict__ s1g, float* __restrict__ s2g,
    int N) {
    __shared__ float4 xs[RPB * 64];  // 32 node rows
    __shared__ float s1l[D], s2l[D];
    const int tid = threadIdx.x;
    s1l[tid] = 0.f;
    s2l[tid] = 0.f;
    const int r0 = blockIdx.x * RPB;
    {
        const float4* nf4 = (const float4*)node_ft;
        const int c4 = tid & 63, e0 = tid >> 6;
#pragma unroll
        for (int p = 0; p < 8; ++p) {
            int rr = e0 + 4 * p;
            int r = r0 + rr;
            xs[rr * 64 + c4] =
                (r < N) ? nf4[(long long)r * 64 + c4] : make_float4(0.f, 0.f, 0.f, 0.f);
        }
    }
    __syncthreads();

    const int dg = tid & 63, rg = tid >> 6;
    float acc[32];
#pragma unroll
    for (int i = 0; i < 32; ++i) acc[i] = 0.f;
    const float4* wle4 = (const float4*)W_le;

    for (int k0 = 0; k0 < 256; k0 += 4) {
        float4 w0 = wle4[(k0 + 0) * 64 + dg];
        float4 w1 = wle4[(k0 + 1) * 64 + dg];
        float4 w2 = wle4[(k0 + 2) * 64 + dg];
        float4 w3 = wle4[(k0 + 3) * 64 + dg];
#pragma unroll
        for (int r8 = 0; r8 < 8; ++r8) {
            float4 xv = xs[(rg * 8 + r8) * 64 + (k0 >> 2)];  // wave-uniform bcast
            acc[r8 * 4 + 0] = fmaf(xv.x, w0.x, fmaf(xv.y, w1.x, fmaf(xv.z, w2.x, fmaf(xv.w, w3.x, acc[r8 * 4 + 0]))));
            acc[r8 * 4 + 1] = fmaf(xv.x, w0.y, fmaf(xv.y, w1.y, fmaf(xv.z, w2.y, fmaf(xv.w, w3.y, acc[r8 * 4 + 1]))));
            acc[r8 * 4 + 2] = fmaf(xv.x, w0.z, fmaf(xv.y, w1.z, fmaf(xv.z, w2.z, fmaf(xv.w, w3.z, acc[r8 * 4 + 2]))));
            acc[r8 * 4 + 3] = fmaf(xv.x, w0.w, fmaf(xv.y, w1.w, fmaf(xv.z, w2.w, fmaf(xv.w, w3.w, acc[r8 * 4 + 3]))));
        }
    }

    const float4 bv = ((const float4*)w_bias)[dg];
    float4* h4 = (float4*)hbuf;
    float s1[4] = {0.f, 0.f, 0.f, 0.f}, s2[4] = {0.f, 0.f, 0.f, 0.f};
#pragma unroll
    for (int r8 = 0; r8 < 8; ++r8) {
        int r = r0 + rg * 8 + r8;
        if (r < N) {
            float nrm = norm[r];
            float4 av = h4[(long long)r * 64 + dg];
            float h0 = fmaf(av.x, nrm, bv.x + acc[r8 * 4 + 0]);
            float h1 = fmaf(av.y, nrm, bv.y + acc[r8 * 4 + 1]);
            float h2 = fmaf(av.z, nrm, bv.z + acc[r8 * 4 + 2]);
            float h3 = fmaf(av.w, nrm, bv.w + acc[r8 * 4 + 3]);
            h4[(long long)r * 64 + dg] = make_float4(h0, h1, h2, h3);
            s1[0] += h0; s2[0] += h0 * h0;
            s1[1] += h1; s2[1] += h1 * h1;
            s1[2] += h2; s2[2] += h2 * h2;
            s1[3] += h3; s2[3] += h3 * h3;
        }
    }
#pragma unroll
    for (int c = 0; c < 4; ++c) {
        atomicAdd(&s1l[dg * 4 + c], s1[c]);
        atomicAdd(&s2l[dg * 4 + c], s2[c]);
    }
    __syncthreads();
    atomAddF(&s1g[tid], s1l[tid]);
    atomAddF(&s2g[tid], s2l[tid]);
}

// ---------------------------------------------------------------------------
// K4: out = tanh((h - mean) * rsqrt(var + eps) * gamma + beta)
// ---------------------------------------------------------------------------
__global__ __launch_bounds__(256) void finalize_kernel(
    float* __restrict__ out, const float* __restrict__ s1g,
    const float* __restrict__ s2g, const float* __restrict__ gamma,
    const float* __restrict__ beta, int N) {
    long long i4 = (long long)blockIdx.x * blockDim.x + threadIdx.x;
    long long tot = (long long)N * D4;
    if (i4 >= tot) return;
    const int dg = (int)(i4 & 63);
    float4 h = ((float4*)out)[i4];
    const float4 s1 = ((const float4*)s1g)[dg];
    const float4 s2 = ((const float4*)s2g)[dg];
    const float4 g = ((const float4*)gamma)[dg];
    const float4 b = ((const float4*)beta)[dg];
    const float invN = 1.f / (float)N;
    float4 o;
    {
        float m = s1.x * invN; float v = s2.x * invN - m * m;
        o.x = tanhf(fmaf(h.x - m, rsqrtf(v + BN_EPS) * g.x, b.x));
    }
    {
        float m = s1.y * invN; float v = s2.y * invN - m * m;
        o.y = tanhf(fmaf(h.y - m, rsqrtf(v + BN_EPS) * g.y, b.y));
    }
    {
        float m = s1.z * invN; float v = s2.z * invN - m * m;
        o.z = tanhf(fmaf(h.z - m, rsqrtf(v + BN_EPS) * g.z, b.z));
    }
    {
        float m = s1.w * invN; float v = s2.w * invN - m * m;
        o.w = tanhf(fmaf(h.w - m, rsqrtf(v + BN_EPS) * g.w, b.w));
    }
    ((float4*)out)[i4] = o;
}

// ---------------------------------------------------------------------------
extern "C" void kernel_launch(void* const* d_in, const int* in_sizes, int n_in,
                              void* d_out, int out_size, void* d_ws, size_t ws_size,
                              hipStream_t stream) {
    const float* node_ft  = (const float*)d_in[0];
    const float* edge_ft  = (const float*)d_in[1];
    const float* norm     = (const float*)d_in[2];
    const float* w_loop   = (const float*)d_in[3];
    const float* w_in     = (const float*)d_in[4];
    const float* loop_rel = (const float*)d_in[5];
    const float* w_bias   = (const float*)d_in[6];
    const float* bn_gamma = (const float*)d_in[7];
    const float* bn_beta  = (const float*)d_in[8];
    const int*   src      = (const int*)d_in[9];
    const int*   dst      = (const int*)d_in[10];

    const int N = in_sizes[2];   // norm has N elements
    const int E = in_sizes[9];   // src has E elements
    float* out = (float*)d_out;

    float* W_le = (float*)d_ws;                          // 256 KB
    float* s1g  = (float*)((char*)d_ws + 262144);        // 1 KB
    float* s2g  = s1g + D;                               // 1 KB

    hipMemsetAsync(d_out, 0, (size_t)N * D * sizeof(float), stream);
    hipMemsetAsync(s1g, 0, 2 * D * sizeof(float), stream);

    wle_kernel<<<D, 256, 0, stream>>>(loop_rel, w_loop, W_le);
    edge_kernel<<<(E + EPB - 1) / EPB, 256, 0, stream>>>(node_ft, edge_ft, w_in,
                                                         src, dst, out, E);
    node_kernel<<<(N + RPB - 1) / RPB, 256, 0, stream>>>(node_ft, W_le, norm,
                                                         w_bias, out, s1g, s2g, N);
    finalize_kernel<<<(int)(((long long)N * D4 + 255) / 256), 256, 0, stream>>>(
        out, s1g, s2g, bn_gamma, bn_beta, N);
}

// Round 2
// 627.284 us; speedup vs baseline: 2.8740x; 2.8740x over previous
//
#include <hip/hip_runtime.h>
#include <hip/hip_bf16.h>

#define NN 50000
#define EE 300000
#define BN_EPS 1e-5f
#define NFW 288            // NF row stride (floats): 258 rounded to 288 (9*32)
#define TWOPI_256 0.024543692606170259f  // 2*pi/256

typedef __attribute__((ext_vector_type(8))) short short8;
typedef __attribute__((ext_vector_type(4))) float f32x4;
#define MFMA16 __builtin_amdgcn_mfma_f32_16x16x32_bf16

// ---- static device scratch (avoids ws_size assumptions) ----
__device__ float g_NF[(size_t)NN * NFW];       // node rfft table, fp32
__device__ float g_LOOPM[(size_t)NN * 256];    // self-loop messages, fp32
__device__ float g_Wle[256 * 256];             // folded loop matrix, fp32
// B operands pre-swizzled into MFMA fragment order: [ks][ntile][lane][8]
__device__ __align__(16) unsigned short g_FB[8 * 20 * 64 * 8];   // rfft matrix F (K=256 -> N=320, cols>=258 zero)
__device__ __align__(16) unsigned short g_CB[9 * 16 * 64 * 8];   // Chat (K=288 -> N=256)
__device__ __align__(16) unsigned short g_WLEB[8 * 16 * 64 * 8]; // W_le (K=256 -> N=256)

__device__ __forceinline__ void atomAddF(float* p, float v) { unsafeAtomicAdd(p, v); }

__device__ __forceinline__ unsigned short f2bf(float x) {
    unsigned int u = __float_as_uint(x);
    u = u + 0x7FFFu + ((u >> 16) & 1u);
    return (unsigned short)(u >> 16);
}
__device__ __forceinline__ float bf2f(unsigned short h) {
    return __uint_as_float(((unsigned int)h) << 16);
}

// ---------------------------------------------------------------------------
// stage 64 rows of a row-major [*,256] fp32 matrix into split-bf16 MFMA
// A-fragment layout in LDS: chunk (m*8+ks)*1024B, lane*16B, elem k&7.
// lane l of tile m, kstep ks holds A[m*16 + (l&15)][32*ks + 8*(l>>4) + e].
// ---------------------------------------------------------------------------
__device__ __forceinline__ void stage_split64(const float* __restrict__ base,
                                              long long row0, long long maxrow,
                                              unsigned short* AH, unsigned short* AL,
                                              int t) {
#pragma unroll
    for (int q = 0; q < 8; ++q) {
        int idx = q * 512 + t;
        int row = idx >> 6, c4 = idx & 63;
        long long gr = row0 + row;
        if (gr >= maxrow) gr = maxrow - 1;
        float4 v = ((const float4*)base)[gr * 64 + c4];
        ushort4 h, l;
        h.x = f2bf(v.x); l.x = f2bf(v.x - bf2f(h.x));
        h.y = f2bf(v.y); l.y = f2bf(v.y - bf2f(h.y));
        h.z = f2bf(v.z); l.z = f2bf(v.z - bf2f(h.z));
        h.w = f2bf(v.w); l.w = f2bf(v.w - bf2f(h.w));
        int off = ((row >> 4) * 8 + (c4 >> 3)) * 1024 +
                  (((((c4 >> 1) & 3) << 4) | (row & 15)) * 16) + (c4 & 1) * 8;
        *(ushort4*)((char*)AH + off) = h;
        *(ushort4*)((char*)AL + off) = l;
    }
}

// ---------------------------------------------------------------------------
// K1: W_le[j][d] = sum_k loop_rel[(j+k)%256] * w_loop[k][d]   (fp32, tiny)
// ---------------------------------------------------------------------------
__global__ __launch_bounds__(256) void wle_kernel(
    const float* __restrict__ loop_rel, const float* __restrict__ w_loop,
    float* __restrict__ W_le) {
    __shared__ float lr[256];
    const int d = threadIdx.x, j = blockIdx.x;
    lr[d] = loop_rel[d];
    __syncthreads();
    float acc = 0.f;
#pragma unroll 4
    for (int k = 0; k < 256; ++k)
        acc = fmaf(lr[(j + k) & 255], w_loop[k * 256 + d], acc);
    W_le[j * 256 + d] = acc;
}

// ---------------------------------------------------------------------------
// pack F (rfft matrix) into B-fragment order. F[k][2f]=cos(2pi f k/256),
// F[k][2f+1]=-sin(...), cols >= 258 zero. blocks: ks*20+nt
// ---------------------------------------------------------------------------
__global__ __launch_bounds__(512) void fb_pack() {
    int b = blockIdx.x, ks = b / 20, nt = b % 20;
    int t = threadIdx.x, lane = t >> 3, e = t & 7;
    int k = 32 * ks + 8 * (lane >> 4) + e;
    int r2 = nt * 16 + (lane & 15);
    float val = 0.f;
    if (r2 < 258) {
        int f = r2 >> 1;
        int m = (f * k) & 255;
        float s, c;
        sincosf((float)m * TWOPI_256, &s, &c);
        val = (r2 & 1) ? -s : c;
    }
    g_FB[((ks * 20 + nt) * 64 + lane) * 8 + e] = f2bf(val);
}

// ---------------------------------------------------------------------------
// pack Chat into B-fragment order. row 2f = c_f * sum_k cos(2pi f k/256) W[k][:],
// row 2f+1 = -c_f * sum_k sin(...) W[k][:];  c_f = 1/256 (f=0,128) else 2/256.
// blocks: ks*16+nt  (ks<9)
// ---------------------------------------------------------------------------
__global__ __launch_bounds__(512) void cb_pack(const float* __restrict__ w_in) {
    int b = blockIdx.x, ks = b / 16, nt = b % 16;
    int t = threadIdx.x, lane = t >> 3, e = t & 7;
    int kk = 32 * ks + 8 * (lane >> 4) + e;   // r2-dim index
    int d = nt * 16 + (lane & 15);
    float val = 0.f;
    if (kk < 258) {
        int f = kk >> 1;
        float cf = (f == 0 || f == 128) ? (1.f / 256.f) : (2.f / 256.f);
        float acc = 0.f;
        for (int k = 0; k < 256; ++k) {
            int m = (f * k) & 255;
            float s, c;
            sincosf((float)m * TWOPI_256, &s, &c);
            float tr = (kk & 1) ? -s : c;
            acc = fmaf(tr, w_in[k * 256 + d], acc);
        }
        val = cf * acc;
    }
    g_CB[((ks * 16 + nt) * 64 + lane) * 8 + e] = f2bf(val);
}

// pack W_le into B-fragment order. blocks: ks*16+nt (ks<8)
__global__ __launch_bounds__(512) void wleb_pack() {
    int b = blockIdx.x, ks = b / 16, nt = b % 16;
    int t = threadIdx.x, lane = t >> 3, e = t & 7;
    int k = 32 * ks + 8 * (lane >> 4) + e;
    int d = nt * 16 + (lane & 15);
    g_WLEB[((ks * 16 + nt) * 64 + lane) * 8 + e] = f2bf(g_Wle[k * 256 + d]);
}

// ---------------------------------------------------------------------------
// nfloop: per 64 node rows: NF = node @ F (write fp32), LOOPM = node @ W_le.
// 512 thr = 8 waves as 2(M) x 4(N).
// ---------------------------------------------------------------------------
__global__ __launch_bounds__(512, 2) void nfloop_kernel(
    const float* __restrict__ node_ft, int N) {
    __shared__ char smem[64 * 1024 + 16];
    unsigned short* AH = (unsigned short*)smem;
    unsigned short* AL = (unsigned short*)(smem + 32768);
    const int t = threadIdx.x;
    const long long r0 = (long long)blockIdx.x * 64;
    stage_split64(node_ft, r0, N, AH, AL, t);
    __syncthreads();

    const int lane = t & 63, w = t >> 6;
    const int mw = w >> 2, nw = w & 3;
    const int l15 = lane & 15, lg = lane >> 4;

    // GEMM-F: N-tiles 5 per wave (some all-zero pad), K = 256
    {
        f32x4 acc[2][5] = {};
#pragma unroll
        for (int ks = 0; ks < 8; ++ks) {
            short8 ah0 = *(const short8*)((char*)AH + ((2 * mw + 0) * 8 + ks) * 1024 + lane * 16);
            short8 al0 = *(const short8*)((char*)AL + ((2 * mw + 0) * 8 + ks) * 1024 + lane * 16);
            short8 ah1 = *(const short8*)((char*)AH + ((2 * mw + 1) * 8 + ks) * 1024 + lane * 16);
            short8 al1 = *(const short8*)((char*)AL + ((2 * mw + 1) * 8 + ks) * 1024 + lane * 16);
#pragma unroll
            for (int j = 0; j < 5; ++j) {
                int tn = 5 * nw + j;
                short8 bf = *(const short8*)(g_FB + ((size_t)(ks * 20 + tn) * 64 + lane) * 8);
                acc[0][j] = MFMA16(ah0, bf, acc[0][j], 0, 0, 0);
                acc[0][j] = MFMA16(al0, bf, acc[0][j], 0, 0, 0);
                acc[1][j] = MFMA16(ah1, bf, acc[1][j], 0, 0, 0);
                acc[1][j] = MFMA16(al1, bf, acc[1][j], 0, 0, 0);
            }
        }
#pragma unroll
        for (int mt = 0; mt < 2; ++mt)
#pragma unroll
            for (int j = 0; j < 5; ++j) {
                int tn = 5 * nw + j;
                if (tn < 18) {
#pragma unroll
                    for (int r = 0; r < 4; ++r) {
                        int e = (2 * mw + mt) * 16 + lg * 4 + r;
                        long long gr = r0 + e;
                        if (gr < N) g_NF[gr * NFW + tn * 16 + l15] = acc[mt][j][r];
                    }
                }
            }
    }
    // GEMM-W: N-tiles 4 per wave, K = 256
    {
        f32x4 acc[2][4] = {};
#pragma unroll
        for (int ks = 0; ks < 8; ++ks) {
            short8 ah0 = *(const short8*)((char*)AH + ((2 * mw + 0) * 8 + ks) * 1024 + lane * 16);
            short8 al0 = *(const short8*)((char*)AL + ((2 * mw + 0) * 8 + ks) * 1024 + lane * 16);
            short8 ah1 = *(const short8*)((char*)AH + ((2 * mw + 1) * 8 + ks) * 1024 + lane * 16);
            short8 al1 = *(const short8*)((char*)AL + ((2 * mw + 1) * 8 + ks) * 1024 + lane * 16);
#pragma unroll
            for (int j = 0; j < 4; ++j) {
                int tn = 4 * nw + j;
                short8 bf = *(const short8*)(g_WLEB + ((size_t)(ks * 16 + tn) * 64 + lane) * 8);
                acc[0][j] = MFMA16(ah0, bf, acc[0][j], 0, 0, 0);
                acc[0][j] = MFMA16(al0, bf, acc[0][j], 0, 0, 0);
                acc[1][j] = MFMA16(ah1, bf, acc[1][j], 0, 0, 0);
                acc[1][j] = MFMA16(al1, bf, acc[1][j], 0, 0, 0);
            }
        }
#pragma unroll
        for (int mt = 0; mt < 2; ++mt)
#pragma unroll
            for (int j = 0; j < 4; ++j)
#pragma unroll
                for (int r = 0; r < 4; ++r) {
                    int e = (2 * mw + mt) * 16 + lg * 4 + r;
                    long long gr = r0 + e;
                    if (gr < N) g_LOOPM[gr * 256 + (4 * nw + j) * 16 + l15] = acc[mt][j][r];
                }
    }
}

// ---------------------------------------------------------------------------
// edge kernel: 64 edges/block, 512 thr (8 waves = 2M x 4N).
//  EF = y @ F (MFMA)  ->  Z = conj(NF[src]) * EF  ->  msg = Z @ Chat (MFMA)
//  -> atomic scatter to agg[dst].
// ---------------------------------------------------------------------------
__global__ __launch_bounds__(512, 2) void edge_kernel(
    const float* __restrict__ edge_ft, const int* __restrict__ src,
    const int* __restrict__ dst, float* __restrict__ agg, int E) {
    __shared__ char smem[72 * 1024 + 512];
    unsigned short* AH = (unsigned short*)smem;             // 32KB
    unsigned short* AL = (unsigned short*)(smem + 32768);   // 32KB
    unsigned short* ZH = (unsigned short*)smem;             // alias: 36KB
    unsigned short* ZL = (unsigned short*)(smem + 36864);   // 36KB
    int* sds = (int*)(smem + 72 * 1024);
    int* sdd = sds + 64;

    const int t = threadIdx.x;
    const long long ebase = (long long)blockIdx.x * 64;

    if (t < 128) {
        int e = t & 63;
        long long ge = ebase + e;
        if (ge >= E) ge = 0;
        if (t < 64) sds[e] = src[ge];
        else        sdd[e] = dst[ge];
    }
    stage_split64(edge_ft, ebase, E, AH, AL, t);
    __syncthreads();

    const int lane = t & 63, w = t >> 6;
    const int mw = w >> 2, nw = w & 3;
    const int l15 = lane & 15, lg = lane >> 4;
    const bool odd = (l15 & 1);

    // ---- GEMM1: EF tiles ----
    f32x4 acc1[2][5] = {};
#pragma unroll
    for (int ks = 0; ks < 8; ++ks) {
        short8 ah0 = *(const short8*)((char*)AH + ((2 * mw + 0) * 8 + ks) * 1024 + lane * 16);
        short8 al0 = *(const short8*)((char*)AL + ((2 * mw + 0) * 8 + ks) * 1024 + lane * 16);
        short8 ah1 = *(const short8*)((char*)AH + ((2 * mw + 1) * 8 + ks) * 1024 + lane * 16);
        short8 al1 = *(const short8*)((char*)AL + ((2 * mw + 1) * 8 + ks) * 1024 + lane * 16);
#pragma unroll
        for (int j = 0; j < 5; ++j) {
            int tn = 5 * nw + j;
            short8 bf = *(const short8*)(g_FB + ((size_t)(ks * 20 + tn) * 64 + lane) * 8);
            acc1[0][j] = MFMA16(ah0, bf, acc1[0][j], 0, 0, 0);
            acc1[0][j] = MFMA16(al0, bf, acc1[0][j], 0, 0, 0);
            acc1[1][j] = MFMA16(ah1, bf, acc1[1][j], 0, 0, 0);
            acc1[1][j] = MFMA16(al1, bf, acc1[1][j], 0, 0, 0);
        }
    }
    __syncthreads();  // all A reads done; Z region may be overwritten

    // ---- Hadamard: Z = conj(NF[src]) * EF, split-write into A-frag layout ----
#pragma unroll
    for (int mt = 0; mt < 2; ++mt) {
        int tm = 2 * mw + mt;
#pragma unroll
        for (int j = 0; j < 5; ++j) {
            int tn = 5 * nw + j;
            if (tn < 18) {
                int r2 = tn * 16 + l15;
#pragma unroll
                for (int r = 0; r < 4; ++r) {
                    float own = acc1[mt][j][r];
                    float oth = __shfl_xor(own, 1);
                    int e = tm * 16 + lg * 4 + r;
                    int s = sds[e];
                    float2 nf = *(const float2*)(&g_NF[(long long)s * NFW + (r2 & ~1)]);
                    // even col (Re): Zr = Ar*Br + Ai*Bi ; odd col (Im): Zi = Ar*Bi - Ai*Br
                    float z = odd ? (nf.x * own - nf.y * oth) : (nf.x * own + nf.y * oth);
                    unsigned short zh = f2bf(z);
                    unsigned short zl = f2bf(z - bf2f(zh));
                    int off = ((e >> 4) * 9 + (r2 >> 5)) * 1024 +
                              (((((r2 >> 3) & 3) << 4) | (e & 15)) * 16) + (r2 & 7) * 2;
                    *(unsigned short*)((char*)ZH + off) = zh;
                    *(unsigned short*)((char*)ZL + off) = zl;
                }
            }
        }
    }
    __syncthreads();

    // ---- GEMM2: msg = Z @ Chat (K = 288) ----
    f32x4 acc2[2][4] = {};
#pragma unroll
    for (int ks = 0; ks < 9; ++ks) {
        short8 ah0 = *(const short8*)((char*)ZH + ((2 * mw + 0) * 9 + ks) * 1024 + lane * 16);
        short8 al0 = *(const short8*)((char*)ZL + ((2 * mw + 0) * 9 + ks) * 1024 + lane * 16);
        short8 ah1 = *(const short8*)((char*)ZH + ((2 * mw + 1) * 9 + ks) * 1024 + lane * 16);
        short8 al1 = *(const short8*)((char*)ZL + ((2 * mw + 1) * 9 + ks) * 1024 + lane * 16);
#pragma unroll
        for (int j = 0; j < 4; ++j) {
            int tn = 4 * nw + j;
            short8 bf = *(const short8*)(g_CB + ((size_t)(ks * 16 + tn) * 64 + lane) * 8);
            acc2[0][j] = MFMA16(ah0, bf, acc2[0][j], 0, 0, 0);
            acc2[0][j] = MFMA16(al0, bf, acc2[0][j], 0, 0, 0);
            acc2[1][j] = MFMA16(ah1, bf, acc2[1][j], 0, 0, 0);
            acc2[1][j] = MFMA16(al1, bf, acc2[1][j], 0, 0, 0);
        }
    }

    // ---- scatter ----
#pragma unroll
    for (int mt = 0; mt < 2; ++mt)
#pragma unroll
        for (int j = 0; j < 4; ++j)
#pragma unroll
            for (int r = 0; r < 4; ++r) {
                int e = (2 * mw + mt) * 16 + lg * 4 + r;
                if (ebase + e < E) {
                    int dr = sdd[e];
                    int d = (4 * nw + j) * 16 + l15;
                    atomAddF(agg + (long long)dr * 256 + d, acc2[mt][j][r]);
                }
            }
}

// ---------------------------------------------------------------------------
// combine: h = agg*norm + bias + loop_msg (in place over agg in d_out) + BN stats
// ---------------------------------------------------------------------------
__global__ __launch_bounds__(256) void combine_kernel(
    const float* __restrict__ norm, const float* __restrict__ w_bias,
    float* __restrict__ hbuf, float* __restrict__ s1g, float* __restrict__ s2g,
    int N) {
    __shared__ float s1l[256], s2l[256];
    const int tid = threadIdx.x;
    s1l[tid] = 0.f;
    s2l[tid] = 0.f;
    __syncthreads();
    const int r0 = blockIdx.x * 32;
    const int dg = tid & 63, rg = tid >> 6;
    const float4 bv = ((const float4*)w_bias)[dg];
    float4* h4 = (float4*)hbuf;
    const float4* lp4 = (const float4*)g_LOOPM;
    float s1[4] = {0.f, 0.f, 0.f, 0.f}, s2[4] = {0.f, 0.f, 0.f, 0.f};
#pragma unroll
    for (int r8 = 0; r8 < 8; ++r8) {
        int r = r0 + rg * 8 + r8;
        if (r < N) {
            float nrm = norm[r];
            float4 av = h4[(long long)r * 64 + dg];
            float4 lv = lp4[(long long)r * 64 + dg];
            float h0 = fmaf(av.x, nrm, bv.x + lv.x);
            float h1 = fmaf(av.y, nrm, bv.y + lv.y);
            float h2 = fmaf(av.z, nrm, bv.z + lv.z);
            float h3 = fmaf(av.w, nrm, bv.w + lv.w);
            h4[(long long)r * 64 + dg] = make_float4(h0, h1, h2, h3);
            s1[0] += h0; s2[0] += h0 * h0;
            s1[1] += h1; s2[1] += h1 * h1;
            s1[2] += h2; s2[2] += h2 * h2;
            s1[3] += h3; s2[3] += h3 * h3;
        }
    }
#pragma unroll
    for (int c = 0; c < 4; ++c) {
        atomicAdd(&s1l[dg * 4 + c], s1[c]);
        atomicAdd(&s2l[dg * 4 + c], s2[c]);
    }
    __syncthreads();
    atomAddF(&s1g[tid], s1l[tid]);
    atomAddF(&s2g[tid], s2l[tid]);
}

// ---------------------------------------------------------------------------
// finalize: out = tanh((h - mean) * rsqrt(var + eps) * gamma + beta)
// ---------------------------------------------------------------------------
__global__ __launch_bounds__(256) void finalize_kernel(
    float* __restrict__ out, const float* __restrict__ s1g,
    const float* __restrict__ s2g, const float* __restrict__ gamma,
    const float* __restrict__ beta, int N) {
    long long i4 = (long long)blockIdx.x * blockDim.x + threadIdx.x;
    long long tot = (long long)N * 64;
    if (i4 >= tot) return;
    const int dg = (int)(i4 & 63);
    float4 h = ((float4*)out)[i4];
    const float4 s1 = ((const float4*)s1g)[dg];
    const float4 s2 = ((const float4*)s2g)[dg];
    const float4 g = ((const float4*)gamma)[dg];
    const float4 b = ((const float4*)beta)[dg];
    const float invN = 1.f / (float)N;
    float4 o;
    { float m = s1.x * invN; float v = s2.x * invN - m * m;
      o.x = tanhf(fmaf(h.x - m, rsqrtf(v + BN_EPS) * g.x, b.x)); }
    { float m = s1.y * invN; float v = s2.y * invN - m * m;
      o.y = tanhf(fmaf(h.y - m, rsqrtf(v + BN_EPS) * g.y, b.y)); }
    { float m = s1.z * invN; float v = s2.z * invN - m * m;
      o.z = tanhf(fmaf(h.z - m, rsqrtf(v + BN_EPS) * g.z, b.z)); }
    { float m = s1.w * invN; float v = s2.w * invN - m * m;
      o.w = tanhf(fmaf(h.w - m, rsqrtf(v + BN_EPS) * g.w, b.w)); }
    ((float4*)out)[i4] = o;
}

// ---------------------------------------------------------------------------
extern "C" void kernel_launch(void* const* d_in, const int* in_sizes, int n_in,
                              void* d_out, int out_size, void* d_ws, size_t ws_size,
                              hipStream_t stream) {
    const float* node_ft  = (const float*)d_in[0];
    const float* edge_ft  = (const float*)d_in[1];
    const float* norm     = (const float*)d_in[2];
    const float* w_loop   = (const float*)d_in[3];
    const float* w_in     = (const float*)d_in[4];
    const float* loop_rel = (const float*)d_in[5];
    const float* w_bias   = (const float*)d_in[6];
    const float* bn_gamma = (const float*)d_in[7];
    const float* bn_beta  = (const float*)d_in[8];
    const int*   src      = (const int*)d_in[9];
    const int*   dst      = (const int*)d_in[10];

    const int N = in_sizes[2];
    const int E = in_sizes[9];
    float* out = (float*)d_out;

    float* s1g = (float*)d_ws;
    float* s2g = s1g + 256;

    hipMemsetAsync(d_out, 0, (size_t)N * 256 * sizeof(float), stream);
    hipMemsetAsync(d_ws, 0, 512 * sizeof(float), stream);

    float* Wle_ptr = nullptr;
    hipGetSymbolAddress((void**)&Wle_ptr, HIP_SYMBOL(g_Wle));

    wle_kernel<<<256, 256, 0, stream>>>(loop_rel, w_loop, Wle_ptr);
    fb_pack<<<8 * 20, 512, 0, stream>>>();
    cb_pack<<<9 * 16, 512, 0, stream>>>(w_in);
    wleb_pack<<<8 * 16, 512, 0, stream>>>();
    nfloop_kernel<<<(N + 63) / 64, 512, 0, stream>>>(node_ft, N);
    edge_kernel<<<(E + 63) / 64, 512, 0, stream>>>(edge_ft, src, dst, out, E);
    combine_kernel<<<(N + 31) / 32, 256, 0, stream>>>(norm, w_bias, out, s1g, s2g, N);
    finalize_kernel<<<(int)(((long long)N * 64 + 255) / 256), 256, 0, stream>>>(
        out, s1g, s2g, bn_gamma, bn_beta, N);
}

// Round 3
// 546.996 us; speedup vs baseline: 3.2958x; 1.1468x over previous
//
#include <hip/hip_runtime.h>
#include <hip/hip_bf16.h>

#define NN 50000
#define BN_EPS 1e-5f
#define NFW 288            // NF row stride in fp16 elems (258 rounded up)
#define TWOPI_256 0.024543692606170259f  // 2*pi/256

typedef __attribute__((ext_vector_type(8))) _Float16 half8;
typedef __attribute__((ext_vector_type(2))) _Float16 half2v;
typedef __attribute__((ext_vector_type(4))) float f32x4;
#define MFMA16F __builtin_amdgcn_mfma_f32_16x16x32_f16

// ---- static device scratch ----
__device__ __align__(16) _Float16 g_NF[(size_t)NN * NFW];  // node rfft table, fp16
__device__ float g_LOOPM[(size_t)NN * 256];                // self-loop messages, fp32
__device__ float g_Wle[256 * 256];                         // folded loop matrix, fp32
// B operands pre-swizzled into MFMA fragment order: [ks][ntile][lane][8]
__device__ __align__(16) unsigned short g_FB[8 * 20 * 64 * 8];   // rfft matrix F
__device__ __align__(16) unsigned short g_CB[9 * 16 * 64 * 8];   // Chat
__device__ __align__(16) unsigned short g_WLEB[8 * 16 * 64 * 8]; // W_le

__device__ __forceinline__ void atomAddF(float* p, float v) { unsafeAtomicAdd(p, v); }

__device__ __forceinline__ unsigned short f2hu(float x) {
    union { _Float16 f; unsigned short u; } c;
    c.f = (_Float16)x;
    return c.u;
}

// ---------------------------------------------------------------------------
// stage 64 rows of a row-major [*,256] fp32 matrix into fp16 MFMA A-fragments.
// chunk (m*8+ks)*1024B; within chunk, lane l's 16B at (l*16)^(ks<<4) (XOR
// swizzle spreads stage writes across banks; reads permute identically).
// lane l of tile m, kstep ks holds A[m*16+(l&15)][32*ks+8*(l>>4)+e].
// ---------------------------------------------------------------------------
__device__ __forceinline__ void stage_h64(const float* __restrict__ base,
                                          long long row0, long long maxrow,
                                          unsigned short* A, int t) {
#pragma unroll
    for (int q = 0; q < 8; ++q) {
        int idx = q * 512 + t;
        int row = idx >> 6, c4 = idx & 63;
        long long gr = row0 + row;
        if (gr >= maxrow) gr = maxrow - 1;
        float4 v = ((const float4*)base)[gr * 64 + c4];
        union { _Float16 f[4]; ushort4 u; } r;
        r.f[0] = (_Float16)v.x; r.f[1] = (_Float16)v.y;
        r.f[2] = (_Float16)v.z; r.f[3] = (_Float16)v.w;
        int ks = c4 >> 3;
        int off = ((row >> 4) * 8 + ks) * 1024 +
                  ((((((c4 >> 1) & 3) << 4) | (row & 15)) * 16) ^ (ks << 4)) +
                  (c4 & 1) * 8;
        *(ushort4*)((char*)A + off) = r.u;
    }
}

// ---------------------------------------------------------------------------
// K1: W_le[j][d] = sum_k loop_rel[(j+k)%256] * w_loop[k][d]   (fp32, tiny)
// ---------------------------------------------------------------------------
__global__ __launch_bounds__(256) void wle_kernel(
    const float* __restrict__ loop_rel, const float* __restrict__ w_loop,
    float* __restrict__ W_le) {
    __shared__ float lr[256];
    const int d = threadIdx.x, j = blockIdx.x;
    lr[d] = loop_rel[d];
    __syncthreads();
    float acc = 0.f;
#pragma unroll 4
    for (int k = 0; k < 256; ++k)
        acc = fmaf(lr[(j + k) & 255], w_loop[k * 256 + d], acc);
    W_le[j * 256 + d] = acc;
}

// ---------------------------------------------------------------------------
// pack F (rfft matrix) into B-fragment order, fp16.
// ---------------------------------------------------------------------------
__global__ __launch_bounds__(512) void fb_pack() {
    int b = blockIdx.x, ks = b / 20, nt = b % 20;
    int t = threadIdx.x, lane = t >> 3, e = t & 7;
    int k = 32 * ks + 8 * (lane >> 4) + e;
    int r2 = nt * 16 + (lane & 15);
    float val = 0.f;
    if (r2 < 258) {
        int f = r2 >> 1;
        int m = (f * k) & 255;
        float s, c;
        sincosf((float)m * TWOPI_256, &s, &c);
        val = (r2 & 1) ? -s : c;
    }
    g_FB[((ks * 20 + nt) * 64 + lane) * 8 + e] = f2hu(val);
}

// ---------------------------------------------------------------------------
// pack Chat into B-fragment order, fp16. LDS trig tables kill the sincos cost.
// ---------------------------------------------------------------------------
__global__ __launch_bounds__(512) void cb_pack(const float* __restrict__ w_in) {
    __shared__ float ct[256], st[256];
    int t = threadIdx.x;
    if (t < 256) {
        float s, c;
        sincosf((float)t * TWOPI_256, &s, &c);
        ct[t] = c; st[t] = s;
    }
    __syncthreads();
    int b = blockIdx.x, ks = b / 16, nt = b % 16;
    int lane = t >> 3, e = t & 7;
    int kk = 32 * ks + 8 * (lane >> 4) + e;
    int d = nt * 16 + (lane & 15);
    float val = 0.f;
    if (kk < 258) {
        int f = kk >> 1;
        float cf = (f == 0 || f == 128) ? (1.f / 256.f) : (2.f / 256.f);
        const float* tab = (kk & 1) ? st : ct;
        float sgn = (kk & 1) ? -1.f : 1.f;
        float acc = 0.f;
        for (int k = 0; k < 256; ++k)
            acc = fmaf(tab[(f * k) & 255], w_in[k * 256 + d], acc);
        val = cf * sgn * acc;
    }
    g_CB[((ks * 16 + nt) * 64 + lane) * 8 + e] = f2hu(val);
}

// pack W_le into B-fragment order, fp16.
__global__ __launch_bounds__(512) void wleb_pack() {
    int b = blockIdx.x, ks = b / 16, nt = b % 16;
    int t = threadIdx.x, lane = t >> 3, e = t & 7;
    int k = 32 * ks + 8 * (lane >> 4) + e;
    int d = nt * 16 + (lane & 15);
    g_WLEB[((ks * 16 + nt) * 64 + lane) * 8 + e] = f2hu(g_Wle[k * 256 + d]);
}

// ---------------------------------------------------------------------------
// nfloop: per 64 node rows: NF = node @ F (store fp16), LOOPM = node @ W_le.
// 512 thr = 8 waves as 2(M) x 4(N).
// ---------------------------------------------------------------------------
__global__ __launch_bounds__(512, 4) void nfloop_kernel(
    const float* __restrict__ node_ft, int N) {
    __shared__ char smem[32768];
    unsigned short* A = (unsigned short*)smem;
    const int t = threadIdx.x;
    const long long r0 = (long long)blockIdx.x * 64;
    stage_h64(node_ft, r0, N, A, t);
    __syncthreads();

    const int lane = t & 63, w = t >> 6;
    const int mw = w >> 2, nw = w & 3;
    const int l15 = lane & 15, lg = lane >> 4;

    // GEMM-F: tiles tn = nw + 4j, tn < 17
    {
        f32x4 acc[2][5] = {};
#pragma unroll
        for (int ks = 0; ks < 8; ++ks) {
            half8 a0 = *(const half8*)((char*)A + ((2 * mw + 0) * 8 + ks) * 1024 + ((lane * 16) ^ (ks << 4)));
            half8 a1 = *(const half8*)((char*)A + ((2 * mw + 1) * 8 + ks) * 1024 + ((lane * 16) ^ (ks << 4)));
#pragma unroll
            for (int j = 0; j < 4; ++j) {
                int tn = nw + 4 * j;
                half8 bf = *(const half8*)(g_FB + ((size_t)(ks * 20 + tn) * 64 + lane) * 8);
                acc[0][j] = MFMA16F(a0, bf, acc[0][j], 0, 0, 0);
                acc[1][j] = MFMA16F(a1, bf, acc[1][j], 0, 0, 0);
            }
            if (nw == 0) {
                half8 bf = *(const half8*)(g_FB + ((size_t)(ks * 20 + 16) * 64 + lane) * 8);
                acc[0][4] = MFMA16F(a0, bf, acc[0][4], 0, 0, 0);
                acc[1][4] = MFMA16F(a1, bf, acc[1][4], 0, 0, 0);
            }
        }
#pragma unroll
        for (int mt = 0; mt < 2; ++mt)
#pragma unroll
            for (int j = 0; j < 5; ++j) {
                int tn = nw + 4 * j;
                if (tn > 16 || (j == 4 && nw != 0)) continue;
                int r2 = tn * 16 + l15;
#pragma unroll
                for (int r = 0; r < 4; ++r) {
                    long long gr = r0 + (2 * mw + mt) * 16 + lg * 4 + r;
                    if (gr < N && r2 < 258)
                        g_NF[gr * NFW + r2] = (_Float16)acc[mt][j][r];
                }
            }
    }
    // GEMM-W: tiles 4*nw+j, K=256, store fp32 LOOPM
    {
        f32x4 acc[2][4] = {};
#pragma unroll
        for (int ks = 0; ks < 8; ++ks) {
            half8 a0 = *(const half8*)((char*)A + ((2 * mw + 0) * 8 + ks) * 1024 + ((lane * 16) ^ (ks << 4)));
            half8 a1 = *(const half8*)((char*)A + ((2 * mw + 1) * 8 + ks) * 1024 + ((lane * 16) ^ (ks << 4)));
#pragma unroll
            for (int j = 0; j < 4; ++j) {
                half8 bf = *(const half8*)(g_WLEB + ((size_t)(ks * 16 + 4 * nw + j) * 64 + lane) * 8);
                acc[0][j] = MFMA16F(a0, bf, acc[0][j], 0, 0, 0);
                acc[1][j] = MFMA16F(a1, bf, acc[1][j], 0, 0, 0);
            }
        }
#pragma unroll
        for (int mt = 0; mt < 2; ++mt)
#pragma unroll
            for (int j = 0; j < 4; ++j)
#pragma unroll
                for (int r = 0; r < 4; ++r) {
                    long long gr = r0 + (2 * mw + mt) * 16 + lg * 4 + r;
                    if (gr < N)
                        g_LOOPM[gr * 256 + (4 * nw + j) * 16 + l15] = acc[mt][j][r];
                }
    }
}

// ---------------------------------------------------------------------------
// edge kernel: 64 edges/block, 512 thr (8 waves = 2M x 4N).
//  EF = y @ F (MFMA) -> Z = conj(NF[src]) * EF -> msg = Z @ Chat (MFMA)
//  -> atomic scatter to agg[dst].  A(32KB) and Z(36KB) alias.
// ---------------------------------------------------------------------------
__global__ __launch_bounds__(512, 6) void edge_kernel(
    const float* __restrict__ edge_ft, const int* __restrict__ src,
    const int* __restrict__ dst, float* __restrict__ agg, int E) {
    __shared__ char smem[36864 + 512];
    unsigned short* A = (unsigned short*)smem;
    unsigned short* Z = (unsigned short*)smem;
    int* sds = (int*)(smem + 36864);
    int* sdd = sds + 64;

    const int t = threadIdx.x;
    const long long ebase = (long long)blockIdx.x * 64;

    if (t < 128) {
        int e = t & 63;
        long long ge = ebase + e;
        if (ge >= E) ge = 0;
        if (t < 64) sds[e] = src[ge];
        else        sdd[e] = dst[ge];
    }
    stage_h64(edge_ft, ebase, E, A, t);
    __syncthreads();

    const int lane = t & 63, w = t >> 6;
    const int mw = w >> 2, nw = w & 3;
    const int l15 = lane & 15, lg = lane >> 4;
    const bool odd = (l15 & 1);

    // ---- GEMM1: EF tiles (tn = nw + 4j < 17) ----
    f32x4 acc1[2][5] = {};
#pragma unroll
    for (int ks = 0; ks < 8; ++ks) {
        half8 a0 = *(const half8*)((char*)A + ((2 * mw + 0) * 8 + ks) * 1024 + ((lane * 16) ^ (ks << 4)));
        half8 a1 = *(const half8*)((char*)A + ((2 * mw + 1) * 8 + ks) * 1024 + ((lane * 16) ^ (ks << 4)));
#pragma unroll
        for (int j = 0; j < 4; ++j) {
            int tn = nw + 4 * j;
            half8 bf = *(const half8*)(g_FB + ((size_t)(ks * 20 + tn) * 64 + lane) * 8);
            acc1[0][j] = MFMA16F(a0, bf, acc1[0][j], 0, 0, 0);
            acc1[1][j] = MFMA16F(a1, bf, acc1[1][j], 0, 0, 0);
        }
        if (nw == 0) {
            half8 bf = *(const half8*)(g_FB + ((size_t)(ks * 20 + 16) * 64 + lane) * 8);
            acc1[0][4] = MFMA16F(a0, bf, acc1[0][4], 0, 0, 0);
            acc1[1][4] = MFMA16F(a1, bf, acc1[1][4], 0, 0, 0);
        }
    }
    __syncthreads();  // all A reads done; Z may overwrite

    // ---- Hadamard: Z = conj(NF[src]) * EF, fp16 write into A-frag layout ----
    // tiles tn = nw+4j: 0..15 real, 16 partially real (r2<258), 17 zero-fill,
    // 18/19 skipped. Z cols 258..287 must be written as zeros.
#pragma unroll
    for (int mt = 0; mt < 2; ++mt) {
        int tm = 2 * mw + mt;
#pragma unroll
        for (int j = 0; j < 5; ++j) {
            int tn = nw + 4 * j;
            if (tn >= 18) continue;
            int r2 = tn * 16 + l15;
#pragma unroll
            for (int r = 0; r < 4; ++r) {
                int e = tm * 16 + lg * 4 + r;
                float own = acc1[mt][j][r];
                float oth = __shfl_xor(own, 1);
                float z = 0.f;
                if (r2 < 258) {
                    int s = sds[e];
                    half2v nf = *(const half2v*)(g_NF + (long long)s * NFW + (r2 & ~1));
                    float br = (float)nf[0], bi = (float)nf[1];
                    // even col (Re): Xr*Yr + Xi*Yi ; odd col (Im): Xr*Yi - Xi*Yr
                    z = odd ? (br * own - bi * oth) : (br * own + bi * oth);
                }
                int ksz = r2 >> 5;
                int off = ((e >> 4) * 9 + ksz) * 1024 +
                          ((((((r2 >> 3) & 3) << 4) | (e & 15)) * 16) ^ (ksz << 4)) +
                          (r2 & 7) * 2;
                *(unsigned short*)((char*)Z + off) = f2hu(z);
            }
        }
    }
    __syncthreads();

    // ---- GEMM2: msg = Z @ Chat (K = 288) ----
    f32x4 acc2[2][4] = {};
#pragma unroll
    for (int ks = 0; ks < 9; ++ks) {
        half8 a0 = *(const half8*)((char*)Z + ((2 * mw + 0) * 9 + ks) * 1024 + ((lane * 16) ^ (ks << 4)));
        half8 a1 = *(const half8*)((char*)Z + ((2 * mw + 1) * 9 + ks) * 1024 + ((lane * 16) ^ (ks << 4)));
#pragma unroll
        for (int j = 0; j < 4; ++j) {
            half8 bf = *(const half8*)(g_CB + ((size_t)(ks * 16 + 4 * nw + j) * 64 + lane) * 8);
            acc2[0][j] = MFMA16F(a0, bf, acc2[0][j], 0, 0, 0);
            acc2[1][j] = MFMA16F(a1, bf, acc2[1][j], 0, 0, 0);
        }
    }

    // ---- scatter ----
#pragma unroll
    for (int mt = 0; mt < 2; ++mt)
#pragma unroll
        for (int j = 0; j < 4; ++j)
#pragma unroll
            for (int r = 0; r < 4; ++r) {
                int e = (2 * mw + mt) * 16 + lg * 4 + r;
                if (ebase + e < E) {
                    int dr = sdd[e];
                    int d = (4 * nw + j) * 16 + l15;
                    atomAddF(agg + (long long)dr * 256 + d, acc2[mt][j][r]);
                }
            }
}

// ---------------------------------------------------------------------------
// combine: h = agg*norm + bias + loop_msg (in place in d_out) + BN partials
// ---------------------------------------------------------------------------
__global__ __launch_bounds__(256) void combine_kernel(
    const float* __restrict__ norm, const float* __restrict__ w_bias,
    float* __restrict__ hbuf, float* __restrict__ s1g, float* __restrict__ s2g,
    int N) {
    __shared__ float s1l[256], s2l[256];
    const int tid = threadIdx.x;
    s1l[tid] = 0.f;
    s2l[tid] = 0.f;
    __syncthreads();
    const int r0 = blockIdx.x * 32;
    const int dg = tid & 63, rg = tid >> 6;
    const float4 bv = ((const float4*)w_bias)[dg];
    float4* h4 = (float4*)hbuf;
    const float4* lp4 = (const float4*)g_LOOPM;
    float s1[4] = {0.f, 0.f, 0.f, 0.f}, s2[4] = {0.f, 0.f, 0.f, 0.f};
#pragma unroll
    for (int r8 = 0; r8 < 8; ++r8) {
        int r = r0 + rg * 8 + r8;
        if (r < N) {
            float nrm = norm[r];
            float4 av = h4[(long long)r * 64 + dg];
            float4 lv = lp4[(long long)r * 64 + dg];
            float h0 = fmaf(av.x, nrm, bv.x + lv.x);
            float h1 = fmaf(av.y, nrm, bv.y + lv.y);
            float h2 = fmaf(av.z, nrm, bv.z + lv.z);
            float h3 = fmaf(av.w, nrm, bv.w + lv.w);
            h4[(long long)r * 64 + dg] = make_float4(h0, h1, h2, h3);
            s1[0] += h0; s2[0] += h0 * h0;
            s1[1] += h1; s2[1] += h1 * h1;
            s1[2] += h2; s2[2] += h2 * h2;
            s1[3] += h3; s2[3] += h3 * h3;
        }
    }
#pragma unroll
    for (int c = 0; c < 4; ++c) {
        atomicAdd(&s1l[dg * 4 + c], s1[c]);
        atomicAdd(&s2l[dg * 4 + c], s2[c]);
    }
    __syncthreads();
    atomAddF(&s1g[tid], s1l[tid]);
    atomAddF(&s2g[tid], s2l[tid]);
}

// ---------------------------------------------------------------------------
// finalize: out = tanh((h - mean) * rsqrt(var + eps) * gamma + beta)
// ---------------------------------------------------------------------------
__global__ __launch_bounds__(256) void finalize_kernel(
    float* __restrict__ out, const float* __restrict__ s1g,
    const float* __restrict__ s2g, const float* __restrict__ gamma,
    const float* __restrict__ beta, int N) {
    long long i4 = (long long)blockIdx.x * blockDim.x + threadIdx.x;
    long long tot = (long long)N * 64;
    if (i4 >= tot) return;
    const int dg = (int)(i4 & 63);
    float4 h = ((float4*)out)[i4];
    const float4 s1 = ((const float4*)s1g)[dg];
    const float4 s2 = ((const float4*)s2g)[dg];
    const float4 g = ((const float4*)gamma)[dg];
    const float4 b = ((const float4*)beta)[dg];
    const float invN = 1.f / (float)N;
    float4 o;
    { float m = s1.x * invN; float v = s2.x * invN - m * m;
      o.x = tanhf(fmaf(h.x - m, rsqrtf(v + BN_EPS) * g.x, b.x)); }
    { float m = s1.y * invN; float v = s2.y * invN - m * m;
      o.y = tanhf(fmaf(h.y - m, rsqrtf(v + BN_EPS) * g.y, b.y)); }
    { float m = s1.z * invN; float v = s2.z * invN - m * m;
      o.z = tanhf(fmaf(h.z - m, rsqrtf(v + BN_EPS) * g.z, b.z)); }
    { float m = s1.w * invN; float v = s2.w * invN - m * m;
      o.w = tanhf(fmaf(h.w - m, rsqrtf(v + BN_EPS) * g.w, b.w)); }
    ((float4*)out)[i4] = o;
}

// ---------------------------------------------------------------------------
extern "C" void kernel_launch(void* const* d_in, const int* in_sizes, int n_in,
                              void* d_out, int out_size, void* d_ws, size_t ws_size,
                              hipStream_t stream) {
    const float* node_ft  = (const float*)d_in[0];
    const float* edge_ft  = (const float*)d_in[1];
    const float* norm     = (const float*)d_in[2];
    const float* w_loop   = (const float*)d_in[3];
    const float* w_in     = (const float*)d_in[4];
    const float* loop_rel = (const float*)d_in[5];
    const float* w_bias   = (const float*)d_in[6];
    const float* bn_gamma = (const float*)d_in[7];
    const float* bn_beta  = (const float*)d_in[8];
    const int*   src      = (const int*)d_in[9];
    const int*   dst      = (const int*)d_in[10];

    const int N = in_sizes[2];
    const int E = in_sizes[9];
    float* out = (float*)d_out;

    float* s1g = (float*)d_ws;
    float* s2g = s1g + 256;

    hipMemsetAsync(d_out, 0, (size_t)N * 256 * sizeof(float), stream);
    hipMemsetAsync(d_ws, 0, 512 * sizeof(float), stream);

    float* Wle_ptr = nullptr;
    hipGetSymbolAddress((void**)&Wle_ptr, HIP_SYMBOL(g_Wle));

    wle_kernel<<<256, 256, 0, stream>>>(loop_rel, w_loop, Wle_ptr);
    fb_pack<<<8 * 20, 512, 0, stream>>>();
    cb_pack<<<9 * 16, 512, 0, stream>>>(w_in);
    wleb_pack<<<8 * 16, 512, 0, stream>>>();
    nfloop_kernel<<<(N + 63) / 64, 512, 0, stream>>>(node_ft, N);
    edge_kernel<<<(E + 63) / 64, 512, 0, stream>>>(edge_ft, src, dst, out, E);
    combine_kernel<<<(N + 31) / 32, 256, 0, stream>>>(norm, w_bias, out, s1g, s2g, N);
    finalize_kernel<<<(int)(((long long)N * 64 + 255) / 256), 256, 0, stream>>>(
        out, s1g, s2g, bn_gamma, bn_beta, N);
}

// Round 4
// 525.970 us; speedup vs baseline: 3.4276x; 1.0400x over previous
//
#include <hip/hip_runtime.h>
#include <hip/hip_bf16.h>

#define NN 50000
#define BN_EPS 1e-5f
#define NFW 288            // NF row stride in fp16 elems (258 rounded up)
#define TWOPI_256 0.024543692606170259f  // 2*pi/256

typedef __attribute__((ext_vector_type(8))) _Float16 half8;
typedef __attribute__((ext_vector_type(2))) _Float16 half2v;
typedef __attribute__((ext_vector_type(4))) float f32x4;
#define MFMA16F __builtin_amdgcn_mfma_f32_16x16x32_f16

// ---- static device scratch ----
__device__ __align__(16) _Float16 g_NF[(size_t)NN * NFW];  // node rfft table, fp16
__device__ float g_LOOPM[(size_t)NN * 256];                // self-loop messages, fp32
__device__ float g_Wle[256 * 256];                         // folded loop matrix, fp32
// B operands pre-swizzled into MFMA fragment order: [ks][ntile][lane][8]
__device__ __align__(16) unsigned short g_FB[8 * 20 * 64 * 8];   // rfft matrix F
__device__ __align__(16) unsigned short g_CB[9 * 16 * 64 * 8];   // Chat
__device__ __align__(16) unsigned short g_WLEB[8 * 16 * 64 * 8]; // W_le

__device__ __forceinline__ void atomAddF(float* p, float v) { unsafeAtomicAdd(p, v); }

__device__ __forceinline__ unsigned short f2hu(float x) {
    union { _Float16 f; unsigned short u; } c;
    c.f = (_Float16)x;
    return c.u;
}

// ---------------------------------------------------------------------------
// stage 64 rows of a row-major [*,256] fp32 matrix into fp16 MFMA A-fragments.
// chunk (m*8+ks)*1024B; within chunk, lane l's 16B at (l*16)^(ks<<4) (XOR
// swizzle spreads stage writes across banks; reads permute identically).
// lane l of tile m, kstep ks holds A[m*16+(l&15)][32*ks+8*(l>>4)+e].
// ---------------------------------------------------------------------------
__device__ __forceinline__ void stage_h64(const float* __restrict__ base,
                                          long long row0, long long maxrow,
                                          unsigned short* A, int t) {
#pragma unroll
    for (int q = 0; q < 8; ++q) {
        int idx = q * 512 + t;
        int row = idx >> 6, c4 = idx & 63;
        long long gr = row0 + row;
        if (gr >= maxrow) gr = maxrow - 1;
        float4 v = ((const float4*)base)[gr * 64 + c4];
        union { _Float16 f[4]; ushort4 u; } r;
        r.f[0] = (_Float16)v.x; r.f[1] = (_Float16)v.y;
        r.f[2] = (_Float16)v.z; r.f[3] = (_Float16)v.w;
        int ks = c4 >> 3;
        int off = ((row >> 4) * 8 + ks) * 1024 +
                  ((((((c4 >> 1) & 3) << 4) | (row & 15)) * 16) ^ (ks << 4)) +
                  (c4 & 1) * 8;
        *(ushort4*)((char*)A + off) = r.u;
    }
}

// ---------------------------------------------------------------------------
// K1: W_le[j][d] = sum_k loop_rel[(j+k)%256] * w_loop[k][d]   (fp32, tiny)
// ---------------------------------------------------------------------------
__global__ __launch_bounds__(256) void wle_kernel(
    const float* __restrict__ loop_rel, const float* __restrict__ w_loop,
    float* __restrict__ W_le) {
    __shared__ float lr[256];
    const int d = threadIdx.x, j = blockIdx.x;
    lr[d] = loop_rel[d];
    __syncthreads();
    float acc = 0.f;
#pragma unroll 4
    for (int k = 0; k < 256; ++k)
        acc = fmaf(lr[(j + k) & 255], w_loop[k * 256 + d], acc);
    W_le[j * 256 + d] = acc;
}

// ---------------------------------------------------------------------------
// pack F (rfft matrix) into B-fragment order, fp16.
// ---------------------------------------------------------------------------
__global__ __launch_bounds__(512) void fb_pack() {
    int b = blockIdx.x, ks = b / 20, nt = b % 20;
    int t = threadIdx.x, lane = t >> 3, e = t & 7;
    int k = 32 * ks + 8 * (lane >> 4) + e;
    int r2 = nt * 16 + (lane & 15);
    float val = 0.f;
    if (r2 < 258) {
        int f = r2 >> 1;
        int m = (f * k) & 255;
        float s, c;
        sincosf((float)m * TWOPI_256, &s, &c);
        val = (r2 & 1) ? -s : c;
    }
    g_FB[((ks * 20 + nt) * 64 + lane) * 8 + e] = f2hu(val);
}

// ---------------------------------------------------------------------------
// pack Chat into B-fragment order, fp16. LDS trig tables kill the sincos cost.
// ---------------------------------------------------------------------------
__global__ __launch_bounds__(512) void cb_pack(const float* __restrict__ w_in) {
    __shared__ float ct[256], st[256];
    int t = threadIdx.x;
    if (t < 256) {
        float s, c;
        sincosf((float)t * TWOPI_256, &s, &c);
        ct[t] = c; st[t] = s;
    }
    __syncthreads();
    int b = blockIdx.x, ks = b / 16, nt = b % 16;
    int lane = t >> 3, e = t & 7;
    int kk = 32 * ks + 8 * (lane >> 4) + e;
    int d = nt * 16 + (lane & 15);
    float val = 0.f;
    if (kk < 258) {
        int f = kk >> 1;
        float cf = (f == 0 || f == 128) ? (1.f / 256.f) : (2.f / 256.f);
        const float* tab = (kk & 1) ? st : ct;
        float sgn = (kk & 1) ? -1.f : 1.f;
        float acc = 0.f;
        for (int k = 0; k < 256; ++k)
            acc = fmaf(tab[(f * k) & 255], w_in[k * 256 + d], acc);
        val = cf * sgn * acc;
    }
    g_CB[((ks * 16 + nt) * 64 + lane) * 8 + e] = f2hu(val);
}

// pack W_le into B-fragment order, fp16.
__global__ __launch_bounds__(512) void wleb_pack() {
    int b = blockIdx.x, ks = b / 16, nt = b % 16;
    int t = threadIdx.x, lane = t >> 3, e = t & 7;
    int k = 32 * ks + 8 * (lane >> 4) + e;
    int d = nt * 16 + (lane & 15);
    g_WLEB[((ks * 16 + nt) * 64 + lane) * 8 + e] = f2hu(g_Wle[k * 256 + d]);
}

// ---------------------------------------------------------------------------
// nfloop: per 64 node rows: NF = node @ F (store fp16), LOOPM = node @ W_le.
// 512 thr = 8 waves as 2(M) x 4(N).
// ---------------------------------------------------------------------------
__global__ __launch_bounds__(512, 4) void nfloop_kernel(
    const float* __restrict__ node_ft, int N) {
    __shared__ char smem[32768];
    unsigned short* A = (unsigned short*)smem;
    const int t = threadIdx.x;
    const long long r0 = (long long)blockIdx.x * 64;
    stage_h64(node_ft, r0, N, A, t);
    __syncthreads();

    const int lane = t & 63, w = t >> 6;
    const int mw = w >> 2, nw = w & 3;
    const int l15 = lane & 15, lg = lane >> 4;

    // GEMM-F: tiles tn = nw + 4j, tn < 17
    {
        f32x4 acc[2][5] = {};
#pragma unroll
        for (int ks = 0; ks < 8; ++ks) {
            half8 a0 = *(const half8*)((char*)A + ((2 * mw + 0) * 8 + ks) * 1024 + ((lane * 16) ^ (ks << 4)));
            half8 a1 = *(const half8*)((char*)A + ((2 * mw + 1) * 8 + ks) * 1024 + ((lane * 16) ^ (ks << 4)));
#pragma unroll
            for (int j = 0; j < 4; ++j) {
                int tn = nw + 4 * j;
                half8 bf = *(const half8*)(g_FB + ((size_t)(ks * 20 + tn) * 64 + lane) * 8);
                acc[0][j] = MFMA16F(a0, bf, acc[0][j], 0, 0, 0);
                acc[1][j] = MFMA16F(a1, bf, acc[1][j], 0, 0, 0);
            }
            if (nw == 0) {
                half8 bf = *(const half8*)(g_FB + ((size_t)(ks * 20 + 16) * 64 + lane) * 8);
                acc[0][4] = MFMA16F(a0, bf, acc[0][4], 0, 0, 0);
                acc[1][4] = MFMA16F(a1, bf, acc[1][4], 0, 0, 0);
            }
        }
#pragma unroll
        for (int mt = 0; mt < 2; ++mt)
#pragma unroll
            for (int j = 0; j < 5; ++j) {
                int tn = nw + 4 * j;
                if (tn > 16 || (j == 4 && nw != 0)) continue;
                int r2 = tn * 16 + l15;
#pragma unroll
                for (int r = 0; r < 4; ++r) {
                    long long gr = r0 + (2 * mw + mt) * 16 + lg * 4 + r;
                    if (gr < N && r2 < 258)
                        g_NF[gr * NFW + r2] = (_Float16)acc[mt][j][r];
                }
            }
    }
    // GEMM-W: tiles 4*nw+j, K=256, store fp32 LOOPM
    {
        f32x4 acc[2][4] = {};
#pragma unroll
        for (int ks = 0; ks < 8; ++ks) {
            half8 a0 = *(const half8*)((char*)A + ((2 * mw + 0) * 8 + ks) * 1024 + ((lane * 16) ^ (ks << 4)));
            half8 a1 = *(const half8*)((char*)A + ((2 * mw + 1) * 8 + ks) * 1024 + ((lane * 16) ^ (ks << 4)));
#pragma unroll
            for (int j = 0; j < 4; ++j) {
                half8 bf = *(const half8*)(g_WLEB + ((size_t)(ks * 16 + 4 * nw + j) * 64 + lane) * 8);
                acc[0][j] = MFMA16F(a0, bf, acc[0][j], 0, 0, 0);
                acc[1][j] = MFMA16F(a1, bf, acc[1][j], 0, 0, 0);
            }
        }
#pragma unroll
        for (int mt = 0; mt < 2; ++mt)
#pragma unroll
            for (int j = 0; j < 4; ++j)
#pragma unroll
                for (int r = 0; r < 4; ++r) {
                    long long gr = r0 + (2 * mw + mt) * 16 + lg * 4 + r;
                    if (gr < N)
                        g_LOOPM[gr * 256 + (4 * nw + j) * 16 + l15] = acc[mt][j][r];
                }
    }
}

// ---------------------------------------------------------------------------
// edge kernel: 64 edges/block, 512 thr (8 waves = 2M x 4N).
//  EF = y @ F (MFMA) -> Z = conj(NF[src]) * EF -> msg = Z @ Chat (MFMA)
//  -> atomic scatter to agg[dst].  A(32KB) and Z(36KB) alias.
//  NF gather is PREFETCHED into registers before GEMM1 (addresses depend only
//  on src[] + static thread coords) so its latency hides under the MFMAs.
// ---------------------------------------------------------------------------
__global__ __launch_bounds__(512, 4) void edge_kernel(
    const float* __restrict__ edge_ft, const int* __restrict__ src,
    const int* __restrict__ dst, float* __restrict__ agg, int E) {
    __shared__ char smem[36864 + 512];
    unsigned short* A = (unsigned short*)smem;
    unsigned short* Z = (unsigned short*)smem;
    int* sdd = (int*)(smem + 36864);

    const int t = threadIdx.x;
    const long long ebase = (long long)blockIdx.x * 64;
    const int lane = t & 63, w = t >> 6;
    const int mw = w >> 2, nw = w & 3;
    const int l15 = lane & 15, lg = lane >> 4;
    const bool odd = (l15 & 1);

    // ---- src values this thread needs (direct global loads, L1-broadcast) ----
    int srcv[2][4];
#pragma unroll
    for (int mt = 0; mt < 2; ++mt)
#pragma unroll
        for (int r = 0; r < 4; ++r) {
            long long ge = ebase + (2 * mw + mt) * 16 + lg * 4 + r;
            srcv[mt][r] = src[ge < E ? ge : 0];
        }

    if (t < 64) {
        long long ge = ebase + t;
        sdd[t] = dst[ge < E ? ge : 0];
    }
    stage_h64(edge_ft, ebase, E, A, t);

    // ---- NF gather prefetch: issue now, consume after GEMM1 (in-flight
    //      across the barrier; latency hidden under staging + MFMAs) ----
    unsigned int pf[2][5][4];
#pragma unroll
    for (int mt = 0; mt < 2; ++mt)
#pragma unroll
        for (int j = 0; j < 5; ++j) {
            int tn = nw + 4 * j;
            if (tn >= 17) continue;         // tn 17..19: zero region, no load
            int r2 = tn * 16 + l15;
            if (r2 < 258) {                 // pair-uniform predicate
#pragma unroll
                for (int r = 0; r < 4; ++r)
                    pf[mt][j][r] = *(const unsigned int*)(g_NF +
                        (long long)srcv[mt][r] * NFW + (r2 & ~1));
            }
        }
    __syncthreads();

    // ---- GEMM1: EF tiles (tn = nw + 4j < 17) ----
    f32x4 acc1[2][5] = {};
#pragma unroll
    for (int ks = 0; ks < 8; ++ks) {
        half8 a0 = *(const half8*)((char*)A + ((2 * mw + 0) * 8 + ks) * 1024 + ((lane * 16) ^ (ks << 4)));
        half8 a1 = *(const half8*)((char*)A + ((2 * mw + 1) * 8 + ks) * 1024 + ((lane * 16) ^ (ks << 4)));
#pragma unroll
        for (int j = 0; j < 4; ++j) {
            int tn = nw + 4 * j;
            half8 bf = *(const half8*)(g_FB + ((size_t)(ks * 20 + tn) * 64 + lane) * 8);
            acc1[0][j] = MFMA16F(a0, bf, acc1[0][j], 0, 0, 0);
            acc1[1][j] = MFMA16F(a1, bf, acc1[1][j], 0, 0, 0);
        }
        if (nw == 0) {
            half8 bf = *(const half8*)(g_FB + ((size_t)(ks * 20 + 16) * 64 + lane) * 8);
            acc1[0][4] = MFMA16F(a0, bf, acc1[0][4], 0, 0, 0);
            acc1[1][4] = MFMA16F(a1, bf, acc1[1][4], 0, 0, 0);
        }
    }
    __syncthreads();  // all A reads done; Z may overwrite

    // ---- Hadamard: Z = conj(NF[src]) * EF, fp16 write into A-frag layout ----
    // tiles tn = nw+4j: 0..15 real, 16 partially real (r2<258), 17 zero-fill,
    // 18/19 skipped. Z cols 258..287 must be written as zeros.
#pragma unroll
    for (int mt = 0; mt < 2; ++mt) {
        int tm = 2 * mw + mt;
#pragma unroll
        for (int j = 0; j < 5; ++j) {
            int tn = nw + 4 * j;
            if (tn >= 18) continue;
            int r2 = tn * 16 + l15;
#pragma unroll
            for (int r = 0; r < 4; ++r) {
                int e = tm * 16 + lg * 4 + r;
                float z = 0.f;
                if (r2 < 258) {
                    float own = acc1[mt][j][r];
                    float oth = __shfl_xor(own, 1);
                    union { unsigned int u; half2v h; } cv;
                    cv.u = pf[mt][j][r];
                    float br = (float)cv.h[0], bi = (float)cv.h[1];
                    // even col (Re): Xr*Yr + Xi*Yi ; odd col (Im): Xr*Yi - Xi*Yr
                    z = odd ? (br * own - bi * oth) : (br * own + bi * oth);
                }
                int ksz = r2 >> 5;
                int off = ((e >> 4) * 9 + ksz) * 1024 +
                          ((((((r2 >> 3) & 3) << 4) | (e & 15)) * 16) ^ (ksz << 4)) +
                          (r2 & 7) * 2;
                *(unsigned short*)((char*)Z + off) = f2hu(z);
            }
        }
    }
    __syncthreads();

    // ---- GEMM2: msg = Z @ Chat (K = 288) ----
    f32x4 acc2[2][4] = {};
#pragma unroll
    for (int ks = 0; ks < 9; ++ks) {
        half8 a0 = *(const half8*)((char*)Z + ((2 * mw + 0) * 9 + ks) * 1024 + ((lane * 16) ^ (ks << 4)));
        half8 a1 = *(const half8*)((char*)Z + ((2 * mw + 1) * 9 + ks) * 1024 + ((lane * 16) ^ (ks << 4)));
#pragma unroll
        for (int j = 0; j < 4; ++j) {
            half8 bf = *(const half8*)(g_CB + ((size_t)(ks * 16 + 4 * nw + j) * 64 + lane) * 8);
            acc2[0][j] = MFMA16F(a0, bf, acc2[0][j], 0, 0, 0);
            acc2[1][j] = MFMA16F(a1, bf, acc2[1][j], 0, 0, 0);
        }
    }

    // ---- scatter ----
#pragma unroll
    for (int mt = 0; mt < 2; ++mt)
#pragma unroll
        for (int j = 0; j < 4; ++j)
#pragma unroll
            for (int r = 0; r < 4; ++r) {
                int e = (2 * mw + mt) * 16 + lg * 4 + r;
                if (ebase + e < E) {
                    int dr = sdd[e];
                    int d = (4 * nw + j) * 16 + l15;
                    atomAddF(agg + (long long)dr * 256 + d, acc2[mt][j][r]);
                }
            }
}

// ---------------------------------------------------------------------------
// combine: h = agg*norm + bias + loop_msg (in place in d_out) + BN partials
// ---------------------------------------------------------------------------
__global__ __launch_bounds__(256) void combine_kernel(
    const float* __restrict__ norm, const float* __restrict__ w_bias,
    float* __restrict__ hbuf, float* __restrict__ s1g, float* __restrict__ s2g,
    int N) {
    __shared__ float s1l[256], s2l[256];
    const int tid = threadIdx.x;
    s1l[tid] = 0.f;
    s2l[tid] = 0.f;
    __syncthreads();
    const int r0 = blockIdx.x * 32;
    const int dg = tid & 63, rg = tid >> 6;
    const float4 bv = ((const float4*)w_bias)[dg];
    float4* h4 = (float4*)hbuf;
    const float4* lp4 = (const float4*)g_LOOPM;
    float s1[4] = {0.f, 0.f, 0.f, 0.f}, s2[4] = {0.f, 0.f, 0.f, 0.f};
#pragma unroll
    for (int r8 = 0; r8 < 8; ++r8) {
        int r = r0 + rg * 8 + r8;
        if (r < N) {
            float nrm = norm[r];
            float4 av = h4[(long long)r * 64 + dg];
            float4 lv = lp4[(long long)r * 64 + dg];
            float h0 = fmaf(av.x, nrm, bv.x + lv.x);
            float h1 = fmaf(av.y, nrm, bv.y + lv.y);
            float h2 = fmaf(av.z, nrm, bv.z + lv.z);
            float h3 = fmaf(av.w, nrm, bv.w + lv.w);
            h4[(long long)r * 64 + dg] = make_float4(h0, h1, h2, h3);
            s1[0] += h0; s2[0] += h0 * h0;
            s1[1] += h1; s2[1] += h1 * h1;
            s1[2] += h2; s2[2] += h2 * h2;
            s1[3] += h3; s2[3] += h3 * h3;
        }
    }
#pragma unroll
    for (int c = 0; c < 4; ++c) {
        atomicAdd(&s1l[dg * 4 + c], s1[c]);
        atomicAdd(&s2l[dg * 4 + c], s2[c]);
    }
    __syncthreads();
    atomAddF(&s1g[tid], s1l[tid]);
    atomAddF(&s2g[tid], s2l[tid]);
}

// ---------------------------------------------------------------------------
// finalize: out = tanh((h - mean) * rsqrt(var + eps) * gamma + beta)
// ---------------------------------------------------------------------------
__global__ __launch_bounds__(256) void finalize_kernel(
    float* __restrict__ out, const float* __restrict__ s1g,
    const float* __restrict__ s2g, const float* __restrict__ gamma,
    const float* __restrict__ beta, int N) {
    long long i4 = (long long)blockIdx.x * blockDim.x + threadIdx.x;
    long long tot = (long long)N * 64;
    if (i4 >= tot) return;
    const int dg = (int)(i4 & 63);
    float4 h = ((float4*)out)[i4];
    const float4 s1 = ((const float4*)s1g)[dg];
    const float4 s2 = ((const float4*)s2g)[dg];
    const float4 g = ((const float4*)gamma)[dg];
    const float4 b = ((const float4*)beta)[dg];
    const float invN = 1.f / (float)N;
    float4 o;
    { float m = s1.x * invN; float v = s2.x * invN - m * m;
      o.x = tanhf(fmaf(h.x - m, rsqrtf(v + BN_EPS) * g.x, b.x)); }
    { float m = s1.y * invN; float v = s2.y * invN - m * m;
      o.y = tanhf(fmaf(h.y - m, rsqrtf(v + BN_EPS) * g.y, b.y)); }
    { float m = s1.z * invN; float v = s2.z * invN - m * m;
      o.z = tanhf(fmaf(h.z - m, rsqrtf(v + BN_EPS) * g.z, b.z)); }
    { float m = s1.w * invN; float v = s2.w * invN - m * m;
      o.w = tanhf(fmaf(h.w - m, rsqrtf(v + BN_EPS) * g.w, b.w)); }
    ((float4*)out)[i4] = o;
}

// ---------------------------------------------------------------------------
extern "C" void kernel_launch(void* const* d_in, const int* in_sizes, int n_in,
                              void* d_out, int out_size, void* d_ws, size_t ws_size,
                              hipStream_t stream) {
    const float* node_ft  = (const float*)d_in[0];
    const float* edge_ft  = (const float*)d_in[1];
    const float* norm     = (const float*)d_in[2];
    const float* w_loop   = (const float*)d_in[3];
    const float* w_in     = (const float*)d_in[4];
    const float* loop_rel = (const float*)d_in[5];
    const float* w_bias   = (const float*)d_in[6];
    const float* bn_gamma = (const float*)d_in[7];
    const float* bn_beta  = (const float*)d_in[8];
    const int*   src      = (const int*)d_in[9];
    const int*   dst      = (const int*)d_in[10];

    const int N = in_sizes[2];
    const int E = in_sizes[9];
    float* out = (float*)d_out;

    float* s1g = (float*)d_ws;
    float* s2g = s1g + 256;

    hipMemsetAsync(d_out, 0, (size_t)N * 256 * sizeof(float), stream);
    hipMemsetAsync(d_ws, 0, 512 * sizeof(float), stream);

    float* Wle_ptr = nullptr;
    hipGetSymbolAddress((void**)&Wle_ptr, HIP_SYMBOL(g_Wle));

    wle_kernel<<<256, 256, 0, stream>>>(loop_rel, w_loop, Wle_ptr);
    fb_pack<<<8 * 20, 512, 0, stream>>>();
    cb_pack<<<9 * 16, 512, 0, stream>>>(w_in);
    wleb_pack<<<8 * 16, 512, 0, stream>>>();
    nfloop_kernel<<<(N + 63) / 64, 512, 0, stream>>>(node_ft, N);
    edge_kernel<<<(E + 63) / 64, 512, 0, stream>>>(edge_ft, src, dst, out, E);
    combine_kernel<<<(N + 31) / 32, 256, 0, stream>>>(norm, w_bias, out, s1g, s2g, N);
    finalize_kernel<<<(int)(((long long)N * 64 + 255) / 256), 256, 0, stream>>>(
        out, s1g, s2g, bn_gamma, bn_beta, N);
}